// Round 6
// baseline (1344.735 us; speedup 1.0000x reference)
//
#include <hip/hip_runtime.h>
#include <math.h>

#define B_  2
#define T_  4096
#define D_  1024
#define H_  16
#define HD_ 64
#define M_  8192   // B*T

using f32x4  = __attribute__((ext_vector_type(4)))  float;
using f32x16 = __attribute__((ext_vector_type(16))) float;
using bfrag  = __attribute__((ext_vector_type(8)))  short;

__device__ __forceinline__ unsigned short f2bf(float f) {
  union { float f; unsigned u; } v; v.f = f;
  unsigned r = v.u + 0x7FFFu + ((v.u >> 16) & 1u);
  return (unsigned short)(r >> 16);
}

__device__ __forceinline__ unsigned cvt_pk(float lo, float hi) {
  unsigned r;
  asm("v_cvt_pk_bf16_f32 %0, %1, %2" : "=v"(r) : "v"(lo), "v"(hi));
  return r;
}

// exchanges: a' = [a.lo32lanes, b.lo32lanes], b' = [a.hi32lanes, b.hi32lanes]
__device__ __forceinline__ void plswap(unsigned &a, unsigned &b) {
  asm("v_permlane32_swap_b32 %0, %1" : "+v"(a), "+v"(b));
}

__device__ __forceinline__ void async16(const void* g, void* l) {
  __builtin_amdgcn_global_load_lds(
      (const __attribute__((address_space(1))) unsigned int*)g,
      (__attribute__((address_space(3))) unsigned int*)l, 16, 0, 0);
}

// ---------------------------------------------------------------------------
// fp32 -> bf16 conversion of x and the four weight matrices into ws
// ---------------------------------------------------------------------------
__global__ __launch_bounds__(256) void convert_all(
    const float* __restrict__ x, const float* __restrict__ wq,
    const float* __restrict__ wk, const float* __restrict__ wv,
    const float* __restrict__ wo, unsigned short* __restrict__ dst)
{
  const size_t NX = (size_t)M_ * D_ / 4;
  const size_t NW = (size_t)D_ * D_ / 4;
  const size_t total = NX + 4 * NW;
  size_t i = (size_t)blockIdx.x * blockDim.x + threadIdx.x;
  size_t stride = (size_t)gridDim.x * blockDim.x;
  for (size_t v = i; v < total; v += stride) {
    const float4* src;
    if (v < NX) {
      src = (const float4*)x + v;
    } else {
      size_t j = v - NX;
      const float* wp = (j < NW) ? wq : (j < 2*NW) ? wk : (j < 3*NW) ? wv : wo;
      src = (const float4*)wp + (j & (NW - 1));
    }
    float4 f = *src;
    ushort4 u;
    u.x = f2bf(f.x); u.y = f2bf(f.y); u.z = f2bf(f.z); u.w = f2bf(f.w);
    *(ushort4*)(dst + v * 4) = u;
  }
}

// ---------------------------------------------------------------------------
// Fused QKV projection: A[8192,1024] x W[3072,1024]^T  (W = wq|wk|wv).
// ---------------------------------------------------------------------------
__global__ __launch_bounds__(256) void gemm_qkv(
    const unsigned short* __restrict__ A,
    const unsigned short* __restrict__ Ww,
    const float* __restrict__ bq, const float* __restrict__ bk,
    const float* __restrict__ bv,
    unsigned short* __restrict__ Qb, unsigned short* __restrict__ Kb,
    unsigned short* __restrict__ Vtb, float qscale)
{
  __shared__ unsigned short a_t[128 * 64];
  __shared__ unsigned short b_t[128 * 64];
  const int tid = threadIdx.x;
  const int lane = tid & 63;
  const int w = tid >> 6;
  const int lo = lane & 15, hi = lane >> 4;
  const int mbase = blockIdx.x * 128;
  const int nbase = blockIdx.y * 128;
  const int wm = w >> 1, wn = w & 1;
  const int K = D_;

  f32x4 acc[4][4];
  #pragma unroll
  for (int m = 0; m < 4; m++)
    #pragma unroll
    for (int n = 0; n < 4; n++) acc[m][n] = f32x4{0.f, 0.f, 0.f, 0.f};

  for (int k0 = 0; k0 < K; k0 += 64) {
    #pragma unroll
    for (int i = 0; i < 4; i++) {
      const int cb = i * 256 + w * 64;
      const int chunk = cb + lane;
      const int row = chunk >> 3, c8 = chunk & 7;
      async16(A  + (size_t)(mbase + row) * K + k0 + c8 * 8, &a_t[cb * 8]);
      async16(Ww + (size_t)(nbase + row) * K + k0 + c8 * 8, &b_t[cb * 8]);
    }
    __syncthreads();
    #pragma unroll
    for (int kk = 0; kk < 2; kk++) {
      bfrag af[4], bf[4];
      #pragma unroll
      for (int m = 0; m < 4; m++)
        af[m] = *(const bfrag*)&a_t[(wm * 64 + m * 16 + lo) * 64 + kk * 32 + hi * 8];
      #pragma unroll
      for (int n = 0; n < 4; n++)
        bf[n] = *(const bfrag*)&b_t[(wn * 64 + n * 16 + lo) * 64 + kk * 32 + hi * 8];
      #pragma unroll
      for (int m = 0; m < 4; m++)
        #pragma unroll
        for (int n = 0; n < 4; n++)
          acc[m][n] = __builtin_amdgcn_mfma_f32_16x16x32_bf16(af[m], bf[n], acc[m][n], 0, 0, 0);
    }
    __syncthreads();
  }

  const int which = nbase >> 10;                    // 0=Q 1=K 2=V
  const float* bias = (which == 0) ? bq : (which == 1) ? bk : bv;
  const float osc = (which == 0) ? qscale : 1.0f;
  unsigned short* outp = (which == 0) ? Qb : (which == 1) ? Kb : Vtb;
  const int nloc = nbase & 1023;

  float bvv[4];
  #pragma unroll
  for (int n = 0; n < 4; n++) bvv[n] = bias[nloc + wn * 64 + n * 16 + lo];

  #pragma unroll
  for (int m = 0; m < 4; m++) {
    const int rowl = wm * 64 + m * 16 + hi * 4;
    #pragma unroll
    for (int n = 0; n < 4; n++) {
      const int gn = nloc + wn * 64 + n * 16 + lo;
      const int h = gn >> 6, d = gn & 63;
      #pragma unroll
      for (int i = 0; i < 4; i++) {
        const float v = (acc[m][n][i] + bvv[n]) * osc;
        const int gm = mbase + rowl + i;
        const int b = gm >> 12, t = gm & 4095;
        if (which < 2)
          outp[(((size_t)(b * H_ + h) * T_) + t) * HD_ + d] = f2bf(v);
        else
          outp[(((size_t)(b * H_ + h) * HD_) + d) * T_ + t] = f2bf(v);
      }
    }
  }
}

// ---------------------------------------------------------------------------
// Output projection: C = A(MxK bf16) * B(NxK bf16)^T + bias -> f32 (m,n)
// ---------------------------------------------------------------------------
__global__ __launch_bounds__(256) void gemm_out(
    const unsigned short* __restrict__ A,
    const unsigned short* __restrict__ Bw,
    const float* __restrict__ bias,
    float* __restrict__ out,
    int M, int N, int K)
{
  __shared__ unsigned short a_t[128 * 64];
  __shared__ unsigned short b_t[128 * 64];
  const int tid = threadIdx.x;
  const int lane = tid & 63;
  const int w = tid >> 6;
  const int lo = lane & 15, hi = lane >> 4;
  const int mbase = blockIdx.x * 128;
  const int nbase = blockIdx.y * 128;
  const int wm = w >> 1, wn = w & 1;

  f32x4 acc[4][4];
  #pragma unroll
  for (int m = 0; m < 4; m++)
    #pragma unroll
    for (int n = 0; n < 4; n++) acc[m][n] = f32x4{0.f, 0.f, 0.f, 0.f};

  for (int k0 = 0; k0 < K; k0 += 64) {
    #pragma unroll
    for (int i = 0; i < 4; i++) {
      const int cb = i * 256 + w * 64;
      const int chunk = cb + lane;
      const int row = chunk >> 3, c8 = chunk & 7;
      async16(A  + (size_t)(mbase + row) * K + k0 + c8 * 8, &a_t[cb * 8]);
      async16(Bw + (size_t)(nbase + row) * K + k0 + c8 * 8, &b_t[cb * 8]);
    }
    __syncthreads();
    #pragma unroll
    for (int kk = 0; kk < 2; kk++) {
      bfrag af[4], bf[4];
      #pragma unroll
      for (int m = 0; m < 4; m++)
        af[m] = *(const bfrag*)&a_t[(wm * 64 + m * 16 + lo) * 64 + kk * 32 + hi * 8];
      #pragma unroll
      for (int n = 0; n < 4; n++)
        bf[n] = *(const bfrag*)&b_t[(wn * 64 + n * 16 + lo) * 64 + kk * 32 + hi * 8];
      #pragma unroll
      for (int m = 0; m < 4; m++)
        #pragma unroll
        for (int n = 0; n < 4; n++)
          acc[m][n] = __builtin_amdgcn_mfma_f32_16x16x32_bf16(af[m], bf[n], acc[m][n], 0, 0, 0);
    }
    __syncthreads();
  }

  float bvv[4];
  #pragma unroll
  for (int n = 0; n < 4; n++) bvv[n] = bias[nbase + wn * 64 + n * 16 + lo];

  #pragma unroll
  for (int m = 0; m < 4; m++) {
    const int rowl = wm * 64 + m * 16 + hi * 4;
    #pragma unroll
    for (int n = 0; n < 4; n++) {
      const int gn = nbase + wn * 64 + n * 16 + lo;
      #pragma unroll
      for (int i = 0; i < 4; i++)
        out[(size_t)(mbase + rowl + i) * N + gn] = acc[m][n][i] + bvv[n];
    }
  }
}

// ---------------------------------------------------------------------------
// Causal flash attention, K-split, 8-wave blocks for occupancy.
// Grid: 1024 = 32 bh x 32 q-groups (128 rows, heavy first). Block: 512 thr.
// wave w: qhalf = w>>1 (0..3: which 32 q-rows), khalf = w&1 (which 32 keys).
// Partner waves (khalf 0/1) merge partial O/l at the end via LDS (stride 17).
// Shift-free softmax (p = exp2(S), Q pre-scaled by 1/sqrt(hd)*log2e).
// S^T = mfma32(K, Q): lane owns q-col = lane&31; k per reg r:
// k = 32*khalf + (r&3)+8*(r>>2)+4*(lane>>5). P->bf16 via cvt_pk+permlane32;
// O^T = mfma32(V^T, P^T). LDS 16B-chunk XOR swizzle, double-buffered.
// SMEM[4][4096]: K bufs 0/1 at [0],[1]; V bufs at [2],[3].
// ---------------------------------------------------------------------------
__global__ __launch_bounds__(512, 8) void attn_kernel(
    const unsigned short* __restrict__ Qg,
    const unsigned short* __restrict__ Kg,
    const unsigned short* __restrict__ Vtg,
    unsigned short* __restrict__ Og)
{
  __shared__ unsigned short SMEM[4][64 * 64];
  const int tid = threadIdx.x, lane = tid & 63, w = tid >> 6;
  const int l31 = lane & 31, hi5 = lane >> 5;
  const int bh = blockIdx.x & 31;
  const int g = 31 - (blockIdx.x >> 5);        // heavy groups first
  const int qhalf = w >> 1, khalf = w & 1;
  const int a = g * 4 + qhalf;                 // 32-row q-subtile index
  const int qg_lane = g * 128 + qhalf * 32 + l31;
  const int jmax = 2 * g + 1;                  // last staged tile
  const int jw = (a >= khalf) ? ((a - khalf) >> 1) : -1;  // last computed tile
  const int b = bh >> 4, h = bh & 15;

  // Q B-fragments
  bfrag qf[4];
  {
    const unsigned short* qp = Qg + ((size_t)bh * T_ + qg_lane) * HD_;
    #pragma unroll
    for (int s = 0; s < 4; s++)
      qf[s] = *(const bfrag*)(qp + s * 16 + hi5 * 8);
  }

  // hoisted swizzled LDS indices (ushort units)
  int kidx[4], vidx0[2], vidx1[2];
  {
    const int krow = khalf * 32 + l31;
    #pragma unroll
    for (int s = 0; s < 4; s++)
      kidx[s] = krow * 64 + (((2 * s + hi5) ^ (krow & 7)) * 8);
    #pragma unroll
    for (int s2 = 0; s2 < 2; s2++) {
      vidx0[s2] = l31 * 64 + (((khalf * 4 + s2 * 2 + hi5) ^ (l31 & 7)) * 8);
      vidx1[s2] = (32 + l31) * 64 + (((khalf * 4 + s2 * 2 + hi5) ^ (l31 & 7)) * 8);
    }
  }

  // per-thread staging pointers: one 16B chunk per thread per array
  const int row0 = tid >> 3, sc80 = (tid & 7) ^ (row0 & 7);
  const unsigned short* kp0 = Kg  + ((size_t)bh * T_  + row0) * HD_ + sc80 * 8;
  const unsigned short* vp0 = Vtg + ((size_t)bh * HD_ + row0) * T_  + sc80 * 8;

  f32x16 o0, o1;
  #pragma unroll
  for (int r = 0; r < 16; r++) { o0[r] = 0.f; o1[r] = 0.f; }
  float l = 0.f;

  // prologue: stage tile 0 into buf 0
  async16(kp0, &SMEM[0][tid * 8]);
  async16(vp0, &SMEM[2][tid * 8]);
  kp0 += 64 * HD_; vp0 += 64;
  __syncthreads();

  #pragma unroll 2
  for (int j = 0; j <= jmax; ++j) {
    const int buf = j & 1;
    if (j < jmax) {   // prefetch tile j+1 into other buffer
      async16(kp0, &SMEM[buf ^ 1][tid * 8]);
      async16(vp0, &SMEM[2 + (buf ^ 1)][tid * 8]);
      kp0 += 64 * HD_; vp0 += 64;
    }

    if (j <= jw) {
      // ---- S^T subtile = K[khalf] * Q^T over hd=64
      f32x16 st;
      #pragma unroll
      for (int r = 0; r < 16; r++) st[r] = 0.f;
      __builtin_amdgcn_s_setprio(1);
      #pragma unroll
      for (int s = 0; s < 4; s++) {
        bfrag kf = *(const bfrag*)&SMEM[buf][kidx[s]];
        st = __builtin_amdgcn_mfma_f32_32x32x16_bf16(kf, qf[s], st, 0, 0, 0);
      }
      __builtin_amdgcn_s_setprio(0);

      // ---- causal mask (possible only on the wave's last tile)
      if (j == jw) {
        const int thr = qg_lane - 64 * j - 32 * khalf - 4 * hi5;
        #pragma unroll
        for (int r = 0; r < 16; r++) {
          const int kl = (r & 3) + 8 * (r >> 2);
          st[r] = (kl > thr) ? -INFINITY : st[r];
        }
      }

      // ---- p = exp2(S), partial row-sum
      float p16[16];
      #pragma unroll
      for (int r = 0; r < 16; r++) p16[r] = exp2f(st[r]);
      float s8[8];
      #pragma unroll
      for (int r = 0; r < 8; r++) s8[r] = p16[r] + p16[r + 8];
      float rs = ((s8[0] + s8[4]) + (s8[1] + s8[5])) +
                 ((s8[2] + s8[6]) + (s8[3] + s8[7]));
      rs += __shfl_xor(rs, 32);
      l += rs;

      // ---- O^T += V^T[d, keys] * P^T
      #pragma unroll
      for (int S = 0; S < 2; S++) {
        const int r0 = 8 * S;
        unsigned pk0 = cvt_pk(p16[r0 + 0], p16[r0 + 1]);
        unsigned pk1 = cvt_pk(p16[r0 + 2], p16[r0 + 3]);
        unsigned pk2 = cvt_pk(p16[r0 + 4], p16[r0 + 5]);
        unsigned pk3 = cvt_pk(p16[r0 + 6], p16[r0 + 7]);
        plswap(pk0, pk2);
        plswap(pk1, pk3);
        union { unsigned u[4]; bfrag f; } pb;
        pb.u[0] = pk0; pb.u[1] = pk1; pb.u[2] = pk2; pb.u[3] = pk3;
        __builtin_amdgcn_s_setprio(1);
        bfrag vf0 = *(const bfrag*)&SMEM[2 + buf][vidx0[S]];
        o0 = __builtin_amdgcn_mfma_f32_32x32x16_bf16(vf0, pb.f, o0, 0, 0, 0);
        bfrag vf1 = *(const bfrag*)&SMEM[2 + buf][vidx1[S]];
        o1 = __builtin_amdgcn_mfma_f32_32x32x16_bf16(vf1, pb.f, o1, 0, 0, 0);
        __builtin_amdgcn_s_setprio(0);
      }
    }

    __syncthreads();
  }

  // ---- partner-wave (khalf) reduction via LDS (stride 17 = conflict-free)
  float* sm = (float*)&SMEM[0][0];
  const int moff = (qhalf * 64 + lane) * 17;
  // phase A: o0 + l
  if (khalf) {
    #pragma unroll
    for (int r = 0; r < 16; r++) sm[moff + r] = o0[r];
    sm[moff + 16] = l;
  }
  __syncthreads();
  if (!khalf) {
    #pragma unroll
    for (int r = 0; r < 16; r++) o0[r] += sm[moff + r];
    l += sm[moff + 16];
  }
  __syncthreads();
  // phase B: o1
  if (khalf) {
    #pragma unroll
    for (int r = 0; r < 16; r++) sm[moff + r] = o1[r];
  }
  __syncthreads();
  if (!khalf) {
    #pragma unroll
    for (int r = 0; r < 16; r++) o1[r] += sm[moff + r];
    const float inv = 1.0f / l;
    unsigned short* orow = Og + ((size_t)(b * T_ + qg_lane)) * D_ + h * HD_;
    #pragma unroll
    for (int r = 0; r < 16; r += 2) {
      const int d0 = (r & 3) + 8 * (r >> 2) + 4 * hi5;
      unsigned u0 = cvt_pk(o0[r] * inv, o0[r + 1] * inv);
      unsigned u1 = cvt_pk(o1[r] * inv, o1[r + 1] * inv);
      *(unsigned*)(orow + d0)      = u0;
      *(unsigned*)(orow + 32 + d0) = u1;
    }
  }
}

// ---------------------------------------------------------------------------
extern "C" void kernel_launch(void* const* d_in, const int* in_sizes, int n_in,
                              void* d_out, int out_size, void* d_ws, size_t ws_size,
                              hipStream_t stream)
{
  const float* x  = (const float*)d_in[0];
  const float* Wq = (const float*)d_in[1];
  const float* bq = (const float*)d_in[2];
  const float* Wk = (const float*)d_in[3];
  const float* bk = (const float*)d_in[4];
  const float* Wv = (const float*)d_in[5];
  const float* bv = (const float*)d_in[6];
  const float* Wo = (const float*)d_in[7];
  const float* bo = (const float*)d_in[8];

  unsigned short* ws  = (unsigned short*)d_ws;
  unsigned short* xb  = ws;
  unsigned short* wqb = xb  + (size_t)M_ * D_;     // wq|wk|wv contiguous
  unsigned short* wkb = wqb + (size_t)D_ * D_;
  unsigned short* wvb = wkb + (size_t)D_ * D_;
  unsigned short* wob = wvb + (size_t)D_ * D_;
  unsigned short* Qb  = wob + (size_t)D_ * D_;
  unsigned short* Kb  = Qb  + (size_t)M_ * D_;
  unsigned short* Vtb = Kb  + (size_t)M_ * D_;
  unsigned short* AOb = Vtb + (size_t)M_ * D_;

  convert_all<<<2048, 256, 0, stream>>>(x, Wq, Wk, Wv, Wo, xb);

  const float qscale = 0.125f * 1.44269504f;   // 1/sqrt(64) * log2(e)
  dim3 gq(M_ / 128, 3072 / 128);
  gemm_qkv<<<gq, 256, 0, stream>>>(xb, wqb, bq, bk, bv, Qb, Kb, Vtb, qscale);

  attn_kernel<<<1024, 512, 0, stream>>>(Qb, Kb, Vtb, AOb);

  dim3 go(M_ / 128, D_ / 128);
  gemm_out<<<go, 256, 0, stream>>>(AOb, wob, bo, (float*)d_out, M_, D_, D_);
}

// Round 8
// 253.878 us; speedup vs baseline: 5.2968x; 5.2968x over previous
//
#include <hip/hip_runtime.h>
#include <math.h>

#define B_  2
#define T_  4096
#define D_  1024
#define H_  16
#define HD_ 64
#define M_  8192   // B*T

using f32x4  = __attribute__((ext_vector_type(4)))  float;
using f32x16 = __attribute__((ext_vector_type(16))) float;
using bfrag  = __attribute__((ext_vector_type(8)))  short;

__device__ __forceinline__ unsigned short f2bf(float f) {
  union { float f; unsigned u; } v; v.f = f;
  unsigned r = v.u + 0x7FFFu + ((v.u >> 16) & 1u);
  return (unsigned short)(r >> 16);
}

__device__ __forceinline__ unsigned cvt_pk(float lo, float hi) {
  unsigned r;
  asm("v_cvt_pk_bf16_f32 %0, %1, %2" : "=v"(r) : "v"(lo), "v"(hi));
  return r;
}

// a' = [a.lo32lanes, b.lo32lanes], b' = [a.hi32lanes, b.hi32lanes]
// NOTE: operands must be values the compiler cannot prove identical
// (same-value coalescing -> self-swap -> undefined result; R7 NaN).
__device__ __forceinline__ void plswap(unsigned &a, unsigned &b) {
  asm("v_permlane32_swap_b32 %0, %1" : "+v"(a), "+v"(b));
}

__device__ __forceinline__ void async16(const void* g, void* l) {
  __builtin_amdgcn_global_load_lds(
      (const __attribute__((address_space(1))) unsigned int*)g,
      (__attribute__((address_space(3))) unsigned int*)l, 16, 0, 0);
}

// ---------------------------------------------------------------------------
// fp32 -> bf16 conversion of x and the four weight matrices into ws
// ---------------------------------------------------------------------------
__global__ __launch_bounds__(256) void convert_all(
    const float* __restrict__ x, const float* __restrict__ wq,
    const float* __restrict__ wk, const float* __restrict__ wv,
    const float* __restrict__ wo, unsigned short* __restrict__ dst)
{
  const size_t NX = (size_t)M_ * D_ / 4;
  const size_t NW = (size_t)D_ * D_ / 4;
  const size_t total = NX + 4 * NW;
  size_t i = (size_t)blockIdx.x * blockDim.x + threadIdx.x;
  size_t stride = (size_t)gridDim.x * blockDim.x;
  for (size_t v = i; v < total; v += stride) {
    const float4* src;
    if (v < NX) {
      src = (const float4*)x + v;
    } else {
      size_t j = v - NX;
      const float* wp = (j < NW) ? wq : (j < 2*NW) ? wk : (j < 3*NW) ? wv : wo;
      src = (const float4*)wp + (j & (NW - 1));
    }
    float4 f = *src;
    ushort4 u;
    u.x = f2bf(f.x); u.y = f2bf(f.y); u.z = f2bf(f.z); u.w = f2bf(f.w);
    *(ushort4*)(dst + v * 4) = u;
  }
}

// ---------------------------------------------------------------------------
// Fused QKV projection: A[8192,1024] x W[3072,1024]^T  (W = wq|wk|wv).
// ---------------------------------------------------------------------------
__global__ __launch_bounds__(256) void gemm_qkv(
    const unsigned short* __restrict__ A,
    const unsigned short* __restrict__ Ww,
    const float* __restrict__ bq, const float* __restrict__ bk,
    const float* __restrict__ bv,
    unsigned short* __restrict__ Qb, unsigned short* __restrict__ Kb,
    unsigned short* __restrict__ Vtb, float qscale)
{
  __shared__ unsigned short a_t[128 * 64];
  __shared__ unsigned short b_t[128 * 64];
  const int tid = threadIdx.x;
  const int lane = tid & 63;
  const int w = tid >> 6;
  const int lo = lane & 15, hi = lane >> 4;
  const int mbase = blockIdx.x * 128;
  const int nbase = blockIdx.y * 128;
  const int wm = w >> 1, wn = w & 1;
  const int K = D_;

  f32x4 acc[4][4];
  #pragma unroll
  for (int m = 0; m < 4; m++)
    #pragma unroll
    for (int n = 0; n < 4; n++) acc[m][n] = f32x4{0.f, 0.f, 0.f, 0.f};

  for (int k0 = 0; k0 < K; k0 += 64) {
    #pragma unroll
    for (int i = 0; i < 4; i++) {
      const int cb = i * 256 + w * 64;
      const int chunk = cb + lane;
      const int row = chunk >> 3, c8 = chunk & 7;
      async16(A  + (size_t)(mbase + row) * K + k0 + c8 * 8, &a_t[cb * 8]);
      async16(Ww + (size_t)(nbase + row) * K + k0 + c8 * 8, &b_t[cb * 8]);
    }
    __syncthreads();
    #pragma unroll
    for (int kk = 0; kk < 2; kk++) {
      bfrag af[4], bf[4];
      #pragma unroll
      for (int m = 0; m < 4; m++)
        af[m] = *(const bfrag*)&a_t[(wm * 64 + m * 16 + lo) * 64 + kk * 32 + hi * 8];
      #pragma unroll
      for (int n = 0; n < 4; n++)
        bf[n] = *(const bfrag*)&b_t[(wn * 64 + n * 16 + lo) * 64 + kk * 32 + hi * 8];
      #pragma unroll
      for (int m = 0; m < 4; m++)
        #pragma unroll
        for (int n = 0; n < 4; n++)
          acc[m][n] = __builtin_amdgcn_mfma_f32_16x16x32_bf16(af[m], bf[n], acc[m][n], 0, 0, 0);
    }
    __syncthreads();
  }

  const int which = nbase >> 10;                    // 0=Q 1=K 2=V
  const float* bias = (which == 0) ? bq : (which == 1) ? bk : bv;
  const float osc = (which == 0) ? qscale : 1.0f;
  unsigned short* outp = (which == 0) ? Qb : (which == 1) ? Kb : Vtb;
  const int nloc = nbase & 1023;

  float bvv[4];
  #pragma unroll
  for (int n = 0; n < 4; n++) bvv[n] = bias[nloc + wn * 64 + n * 16 + lo];

  #pragma unroll
  for (int m = 0; m < 4; m++) {
    const int rowl = wm * 64 + m * 16 + hi * 4;
    #pragma unroll
    for (int n = 0; n < 4; n++) {
      const int gn = nloc + wn * 64 + n * 16 + lo;
      const int h = gn >> 6, d = gn & 63;
      #pragma unroll
      for (int i = 0; i < 4; i++) {
        const float v = (acc[m][n][i] + bvv[n]) * osc;
        const int gm = mbase + rowl + i;
        const int b = gm >> 12, t = gm & 4095;
        if (which < 2)
          outp[(((size_t)(b * H_ + h) * T_) + t) * HD_ + d] = f2bf(v);
        else
          outp[(((size_t)(b * H_ + h) * HD_) + d) * T_ + t] = f2bf(v);
      }
    }
  }
}

// ---------------------------------------------------------------------------
// Output projection: C = A(MxK bf16) * B(NxK bf16)^T + bias -> f32 (m,n)
// ---------------------------------------------------------------------------
__global__ __launch_bounds__(256) void gemm_out(
    const unsigned short* __restrict__ A,
    const unsigned short* __restrict__ Bw,
    const float* __restrict__ bias,
    float* __restrict__ out,
    int M, int N, int K)
{
  __shared__ unsigned short a_t[128 * 64];
  __shared__ unsigned short b_t[128 * 64];
  const int tid = threadIdx.x;
  const int lane = tid & 63;
  const int w = tid >> 6;
  const int lo = lane & 15, hi = lane >> 4;
  const int mbase = blockIdx.x * 128;
  const int nbase = blockIdx.y * 128;
  const int wm = w >> 1, wn = w & 1;

  f32x4 acc[4][4];
  #pragma unroll
  for (int m = 0; m < 4; m++)
    #pragma unroll
    for (int n = 0; n < 4; n++) acc[m][n] = f32x4{0.f, 0.f, 0.f, 0.f};

  for (int k0 = 0; k0 < K; k0 += 64) {
    #pragma unroll
    for (int i = 0; i < 4; i++) {
      const int cb = i * 256 + w * 64;
      const int chunk = cb + lane;
      const int row = chunk >> 3, c8 = chunk & 7;
      async16(A  + (size_t)(mbase + row) * K + k0 + c8 * 8, &a_t[cb * 8]);
      async16(Bw + (size_t)(nbase + row) * K + k0 + c8 * 8, &b_t[cb * 8]);
    }
    __syncthreads();
    #pragma unroll
    for (int kk = 0; kk < 2; kk++) {
      bfrag af[4], bf[4];
      #pragma unroll
      for (int m = 0; m < 4; m++)
        af[m] = *(const bfrag*)&a_t[(wm * 64 + m * 16 + lo) * 64 + kk * 32 + hi * 8];
      #pragma unroll
      for (int n = 0; n < 4; n++)
        bf[n] = *(const bfrag*)&b_t[(wn * 64 + n * 16 + lo) * 64 + kk * 32 + hi * 8];
      #pragma unroll
      for (int m = 0; m < 4; m++)
        #pragma unroll
        for (int n = 0; n < 4; n++)
          acc[m][n] = __builtin_amdgcn_mfma_f32_16x16x32_bf16(af[m], bf[n], acc[m][n], 0, 0, 0);
    }
    __syncthreads();
  }

  float bvv[4];
  #pragma unroll
  for (int n = 0; n < 4; n++) bvv[n] = bias[nbase + wn * 64 + n * 16 + lo];

  #pragma unroll
  for (int m = 0; m < 4; m++) {
    const int rowl = wm * 64 + m * 16 + hi * 4;
    #pragma unroll
    for (int n = 0; n < 4; n++) {
      const int gn = nbase + wn * 64 + n * 16 + lo;
      #pragma unroll
      for (int i = 0; i < 4; i++)
        out[(size_t)(mbase + rowl + i) * N + gn] = acc[m][n][i] + bvv[n];
    }
  }
}

// ---------------------------------------------------------------------------
// Causal flash attention, K-split: each wave owns a 32x32 S-subtile.
// Grid: 2048 = 32 bh x 64 q-groups (64 rows, heavy first). Block: 4 waves.
// wave w: qhalf = w>>1 (which 32 q-rows), khalf = w&1 (which 32 keys of tile).
// Partner waves (khalf 0/1) merge partial O/l at the end via LDS (stride 17).
// Shift-free softmax (p = exp2(S), Q pre-scaled by 1/sqrt(hd)*log2e).
// S^T = mfma32(K, Q): lane owns q-col = lane&31; k per reg r:
// k = 32*khalf + (r&3)+8*(r>>2)+4*(lane>>5). P->bf16 via cvt_pk+permlane32;
// O^T = mfma32(V^T, P^T). LDS 16B-chunk XOR swizzle, double-buffered.
// launch_bounds(256,5): cap 102 regs; (256,8) spilled the accs (R6).
// ---------------------------------------------------------------------------
__global__ __launch_bounds__(256, 5) void attn_kernel(
    const unsigned short* __restrict__ Qg,
    const unsigned short* __restrict__ Kg,
    const unsigned short* __restrict__ Vtg,
    unsigned short* __restrict__ Og)
{
  __shared__ unsigned short K_lds[2][64 * 64];
  __shared__ unsigned short V_lds[2][64 * 64];   // [d][t_local]
  const int tid = threadIdx.x, lane = tid & 63, w = tid >> 6;
  const int l31 = lane & 31, hi5 = lane >> 5;
  const int bh = blockIdx.x & 31;
  const int qgroup = 63 - (blockIdx.x >> 5);    // heavy groups first
  const int qhalf = w >> 1, khalf = w & 1;
  const int a = qgroup * 2 + qhalf;             // 32-row q-subtile index
  const int qg_lane = qgroup * 64 + qhalf * 32 + l31;
  const int jmax = qgroup;                      // last staged tile
  const int jw = (a >= khalf) ? ((a - khalf) >> 1) : -1;  // last computed tile
  const int b = bh >> 4, h = bh & 15;

  // Q B-fragments
  bfrag qf[4];
  {
    const unsigned short* qp = Qg + ((size_t)bh * T_ + qg_lane) * HD_;
    #pragma unroll
    for (int s = 0; s < 4; s++)
      qf[s] = *(const bfrag*)(qp + s * 16 + hi5 * 8);
  }

  // hoisted swizzled LDS indices (ushort units)
  int kidx[4], vidx0[2], vidx1[2];
  {
    const int krow = khalf * 32 + l31;
    #pragma unroll
    for (int s = 0; s < 4; s++)
      kidx[s] = krow * 64 + (((2 * s + hi5) ^ (krow & 7)) * 8);
    #pragma unroll
    for (int s2 = 0; s2 < 2; s2++) {
      vidx0[s2] = l31 * 64 + (((khalf * 4 + s2 * 2 + hi5) ^ (l31 & 7)) * 8);
      vidx1[s2] = (32 + l31) * 64 + (((khalf * 4 + s2 * 2 + hi5) ^ (l31 & 7)) * 8);
    }
  }

  // per-thread staging pointers (advance per tile)
  const int row0 = tid >> 3,            sc80 = (tid & 7) ^ (row0 & 7);
  const int row1 = (tid + 256) >> 3,    sc81 = (tid & 7) ^ (row1 & 7);
  const unsigned short* kp0 = Kg  + ((size_t)bh * T_  + row0) * HD_ + sc80 * 8;
  const unsigned short* kp1 = Kg  + ((size_t)bh * T_  + row1) * HD_ + sc81 * 8;
  const unsigned short* vp0 = Vtg + ((size_t)bh * HD_ + row0) * T_  + sc80 * 8;
  const unsigned short* vp1 = Vtg + ((size_t)bh * HD_ + row1) * T_  + sc81 * 8;

  f32x16 o0, o1, zacc;
  #pragma unroll
  for (int r = 0; r < 16; r++) { o0[r] = 0.f; o1[r] = 0.f; zacc[r] = 0.f; }
  float l = 0.f;

  // prologue: stage tile 0 into buf 0
  async16(kp0, &K_lds[0][tid * 8]);
  async16(kp1, &K_lds[0][(tid + 256) * 8]);
  async16(vp0, &V_lds[0][tid * 8]);
  async16(vp1, &V_lds[0][(tid + 256) * 8]);
  kp0 += 64 * HD_; kp1 += 64 * HD_; vp0 += 64; vp1 += 64;
  __syncthreads();

  #pragma unroll 2
  for (int j = 0; j <= jmax; ++j) {
    const int buf = j & 1;
    if (j < jmax) {   // prefetch tile j+1 into other buffer
      async16(kp0, &K_lds[buf ^ 1][tid * 8]);
      async16(kp1, &K_lds[buf ^ 1][(tid + 256) * 8]);
      async16(vp0, &V_lds[buf ^ 1][tid * 8]);
      async16(vp1, &V_lds[buf ^ 1][(tid + 256) * 8]);
      kp0 += 64 * HD_; kp1 += 64 * HD_; vp0 += 64; vp1 += 64;
    }

    if (j <= jw) {
      // ---- S^T subtile = K[khalf] * Q^T over hd=64 (first MFMA uses zacc)
      __builtin_amdgcn_s_setprio(1);
      bfrag kf = *(const bfrag*)&K_lds[buf][kidx[0]];
      f32x16 st = __builtin_amdgcn_mfma_f32_32x32x16_bf16(kf, qf[0], zacc, 0, 0, 0);
      #pragma unroll
      for (int s = 1; s < 4; s++) {
        kf = *(const bfrag*)&K_lds[buf][kidx[s]];
        st = __builtin_amdgcn_mfma_f32_32x32x16_bf16(kf, qf[s], st, 0, 0, 0);
      }
      __builtin_amdgcn_s_setprio(0);

      // ---- causal mask (possible only on the wave's last tile)
      if (j == jw) {
        const int thr = qg_lane - 64 * j - 32 * khalf - 4 * hi5;
        #pragma unroll
        for (int r = 0; r < 16; r++) {
          const int kl = (r & 3) + 8 * (r >> 2);
          st[r] = (kl > thr) ? -INFINITY : st[r];
        }
      }

      // ---- p = exp2(S), partial row-sum (cross-half via shfl_xor)
      float p16[16];
      #pragma unroll
      for (int r = 0; r < 16; r++) p16[r] = exp2f(st[r]);
      float s8[8];
      #pragma unroll
      for (int r = 0; r < 8; r++) s8[r] = p16[r] + p16[r + 8];
      float rs = ((s8[0] + s8[4]) + (s8[1] + s8[5])) +
                 ((s8[2] + s8[6]) + (s8[3] + s8[7]));
      rs += __shfl_xor(rs, 32);
      l += rs;

      // ---- O^T += V^T[d, keys] * P^T
      #pragma unroll
      for (int S = 0; S < 2; S++) {
        const int r0 = 8 * S;
        unsigned pk0 = cvt_pk(p16[r0 + 0], p16[r0 + 1]);
        unsigned pk1 = cvt_pk(p16[r0 + 2], p16[r0 + 3]);
        unsigned pk2 = cvt_pk(p16[r0 + 4], p16[r0 + 5]);
        unsigned pk3 = cvt_pk(p16[r0 + 6], p16[r0 + 7]);
        plswap(pk0, pk2);
        plswap(pk1, pk3);
        union { unsigned u[4]; bfrag f; } pb;
        pb.u[0] = pk0; pb.u[1] = pk1; pb.u[2] = pk2; pb.u[3] = pk3;
        __builtin_amdgcn_s_setprio(1);
        bfrag vf0 = *(const bfrag*)&V_lds[buf][vidx0[S]];
        o0 = __builtin_amdgcn_mfma_f32_32x32x16_bf16(vf0, pb.f, o0, 0, 0, 0);
        bfrag vf1 = *(const bfrag*)&V_lds[buf][vidx1[S]];
        o1 = __builtin_amdgcn_mfma_f32_32x32x16_bf16(vf1, pb.f, o1, 0, 0, 0);
        __builtin_amdgcn_s_setprio(0);
      }
    }

    __syncthreads();
  }

  // ---- partner-wave (khalf) reduction via LDS, stride 17 (conflict-free)
  float* sm = (float*)&K_lds[0][0];          // 16 KB region, uses 8.7 KB
  const int moff = (qhalf * 64 + lane) * 17;
  if (khalf) {
    #pragma unroll
    for (int r = 0; r < 16; r++) sm[moff + r] = o0[r];
    sm[moff + 16] = l;
  }
  __syncthreads();
  if (!khalf) {
    #pragma unroll
    for (int r = 0; r < 16; r++) o0[r] += sm[moff + r];
    l += sm[moff + 16];
  }
  __syncthreads();
  if (khalf) {
    #pragma unroll
    for (int r = 0; r < 16; r++) sm[moff + r] = o1[r];
  }
  __syncthreads();
  if (!khalf) {
    #pragma unroll
    for (int r = 0; r < 16; r++) o1[r] += sm[moff + r];
    const float inv = 1.0f / l;
    unsigned short* orow = Og + ((size_t)(b * T_ + qg_lane)) * D_ + h * HD_;
    #pragma unroll
    for (int r = 0; r < 16; r += 2) {
      const int d0 = (r & 3) + 8 * (r >> 2) + 4 * hi5;
      unsigned u0 = cvt_pk(o0[r] * inv, o0[r + 1] * inv);
      unsigned u1 = cvt_pk(o1[r] * inv, o1[r + 1] * inv);
      *(unsigned*)(orow + d0)      = u0;
      *(unsigned*)(orow + 32 + d0) = u1;
    }
  }
}

// ---------------------------------------------------------------------------
extern "C" void kernel_launch(void* const* d_in, const int* in_sizes, int n_in,
                              void* d_out, int out_size, void* d_ws, size_t ws_size,
                              hipStream_t stream)
{
  const float* x  = (const float*)d_in[0];
  const float* Wq = (const float*)d_in[1];
  const float* bq = (const float*)d_in[2];
  const float* Wk = (const float*)d_in[3];
  const float* bk = (const float*)d_in[4];
  const float* Wv = (const float*)d_in[5];
  const float* bv = (const float*)d_in[6];
  const float* Wo = (const float*)d_in[7];
  const float* bo = (const float*)d_in[8];

  unsigned short* ws  = (unsigned short*)d_ws;
  unsigned short* xb  = ws;
  unsigned short* wqb = xb  + (size_t)M_ * D_;     // wq|wk|wv contiguous
  unsigned short* wkb = wqb + (size_t)D_ * D_;
  unsigned short* wvb = wkb + (size_t)D_ * D_;
  unsigned short* wob = wvb + (size_t)D_ * D_;
  unsigned short* Qb  = wob + (size_t)D_ * D_;
  unsigned short* Kb  = Qb  + (size_t)M_ * D_;
  unsigned short* Vtb = Kb  + (size_t)M_ * D_;
  unsigned short* AOb = Vtb + (size_t)M_ * D_;

  convert_all<<<2048, 256, 0, stream>>>(x, Wq, Wk, Wv, Wo, xb);

  const float qscale = 0.125f * 1.44269504f;   // 1/sqrt(64) * log2(e)
  dim3 gq(M_ / 128, 3072 / 128);
  gemm_qkv<<<gq, 256, 0, stream>>>(xb, wqb, bq, bk, bv, Qb, Kb, Vtb, qscale);

  attn_kernel<<<2048, 256, 0, stream>>>(Qb, Kb, Vtb, AOb);

  dim3 go(M_ / 128, D_ / 128);
  gemm_out<<<go, 256, 0, stream>>>(AOb, wob, bo, (float*)d_out, M_, D_, D_);
}